// Round 9
// baseline (22.352 us; speedup 1.0000x reference)
//
#include <hip/hip_runtime.h>

namespace {
constexpr int B = 8, T = 12, N = 325, C = 32, K = 100;
constexpr int NPB = 5;                        // nodes per block; 325 = 5*65
constexpr int NPAIRS = N / NPB;               // 65
constexpr float EPSF = 1e-5f;
constexpr float MIN_NORM = 1e-15f;
}

typedef float f32x16 __attribute__((ext_vector_type(16)));

// block = 640 threads = 10 waves. wave -> (node nl = w>>1, k-half h = w&1).
// lane -> k = h*64+lane. x row is wave-uniform -> SGPRs via forced s_load;
// dot = v_fma with SGPR src (no LDS/VMEM issue for x). y per-lane in VGPRs.
__global__ __launch_bounds__(640) void hcd_kernel(
    const float* __restrict__ x_g,       // [B,T,N,C]
    const float* __restrict__ cw,        // [K,C]
    const float* __restrict__ cptr,      // [1]
    float* __restrict__ out0,            // [B,N,K]
    float* __restrict__ out1)            // [B,T,N,K]
{
  __shared__ float x2l[NPB][T];

  const int tid = threadIdx.x;
  const int b  = blockIdx.x / NPAIRS;
  const int np = blockIdx.x % NPAIRS;
  const int n0 = np * NPB;
  const float c  = cptr[0];
  const float sc = sqrtf(c);
  const float inv_c4 = 4.f / c;                 // (2/sqrt(c))^2
  const float HLN2 = 0.34657359028f;            // ln2/2
  const float TLOG2E = 2.88539008178f;          // 2*log2(e)

  // ---- x squared norms for the block's 60 (n,t) rows ----
  if (tid < NPB * T) {
    int nl_ = tid / T, t = tid - nl_ * T;
    const float* xr = x_g + ((size_t)(b * T + t) * N + (n0 + nl_)) * C;
    float s = 0.f;
    #pragma unroll
    for (int q = 0; q < C / 4; ++q) {
      float4 v = *(const float4*)(xr + 4 * q);
      s = fmaf(v.x, v.x, s); s = fmaf(v.y, v.y, s);
      s = fmaf(v.z, v.z, s); s = fmaf(v.w, v.w, s);
    }
    x2l[nl_][t] = s;
  }

  // ---- per-lane expmap0 of centroid kc (global reads, L2-hot) ----
  const int wave = tid >> 6;
  const int lane = tid & 63;
  const int nl = wave >> 1;            // 0..4, wave-uniform
  const int h  = wave & 1;
  const int k  = h * 64 + lane;        // 0..127
  const int kc = (k < K) ? k : K - 1;
  const bool pred = (k < K);

  float yk[C];
  float y2;
  {
    const float* yr = cw + kc * C;
    #pragma unroll
    for (int q = 0; q < C / 4; ++q) {
      float4 v = *(const float4*)(yr + 4 * q);
      yk[4*q+0] = v.x; yk[4*q+1] = v.y; yk[4*q+2] = v.z; yk[4*q+3] = v.w;
    }
    float u2 = 0.f;
    #pragma unroll
    for (int i = 0; i < C; ++i) u2 = fmaf(yk[i], yk[i], u2);
    float z = sc * fmaxf(sqrtf(u2), MIN_NORM);
    float E  = exp2f(z * TLOG2E);                       // e^(2z)
    float th = (E - 1.f) * __builtin_amdgcn_rcpf(E + 1.f);
    float f  = th * __builtin_amdgcn_rcpf(z);
    #pragma unroll
    for (int i = 0; i < C; ++i) yk[i] *= f;
    y2 = f * f * u2;
  }
  __syncthreads();

  const int n = n0 + nl;               // wave-uniform
  int rowbase = ((b * T) * N + n) * C; // t = 0
  rowbase = __builtin_amdgcn_readfirstlane(rowbase);
  const float* xbase = x_g + rowbase;

  const float c2 = c * c;
  const float tc = 2.f * c;
  float ssum = 0.f;

  #pragma unroll
  for (int t = 0; t < T; ++t) {
    const float* xt = xbase + t * (N * C);   // uniform pointer
    f32x16 xa, xv;
    asm volatile(
        "s_load_dwordx16 %0, %2, 0x0\n\t"
        "s_load_dwordx16 %1, %2, 0x40\n\t"
        "s_waitcnt lgkmcnt(0)"
        : "=&s"(xa), "=&s"(xv)
        : "s"(xt));

    float a0 = 0.f, a1 = 0.f, a2 = 0.f, a3 = 0.f;
    #pragma unroll
    for (int i = 0; i < 16; i += 4) {
      a0 = fmaf(xa[i+0], yk[i+0], a0);
      a1 = fmaf(xa[i+1], yk[i+1], a1);
      a2 = fmaf(xa[i+2], yk[i+2], a2);
      a3 = fmaf(xa[i+3], yk[i+3], a3);
    }
    #pragma unroll
    for (int i = 0; i < 16; i += 4) {
      a0 = fmaf(xv[i+0], yk[16+i+0], a0);
      a1 = fmaf(xv[i+1], yk[16+i+1], a1);
      a2 = fmaf(xv[i+2], yk[16+i+2], a2);
      a3 = fmaf(xv[i+3], yk[16+i+3], a3);
    }
    const float dot = (a0 + a1) + (a2 + a3);

    const float x2 = x2l[nl][t];                       // broadcast ds_read
    const float xy = -dot;                             // dot(-x, y)
    const float A  = fmaf(tc, xy, 1.f) + c * y2;       // 1 + 2c*xy + c*y2
    const float Bc = 1.f - c * x2;                     // 1 - c*x2
    float num2 = A * A * x2 + Bc * Bc * y2 + 2.f * A * Bc * xy;
    num2 = fmaxf(num2, 0.f);
    float den = fmaf(c2 * x2, y2, fmaf(tc, xy, 1.f));
    den = fmaxf(den, MIN_NORM);
    float s_ = sc * __builtin_amdgcn_sqrtf(num2);
    s_ = fminf(s_, (1.f - EPSF) * den);                // z <= 1-eps
    float r  = (den + s_) * __builtin_amdgcn_rcpf(den - s_);
    float at = HLN2 * __builtin_amdgcn_logf(r);        // atanh(z)
    float d2 = inv_c4 * at * at;
    ssum += d2;
    if (pred)
      out1[(((size_t)(b * T + t)) * N + n) * K + k] = d2;
  }
  if (pred)
    out0[((size_t)b * N + n) * K + k] = ssum * (1.f / (float)N);
}

extern "C" void kernel_launch(void* const* d_in, const int* in_sizes, int n_in,
                              void* d_out, int out_size, void* d_ws, size_t ws_size,
                              hipStream_t stream) {
  // identify inputs by size (order-proof): node 998400, centroids 3200, c 1
  const void* xp = nullptr; const void* cwp = nullptr; const void* cp = nullptr;
  for (int i = 0; i < n_in; ++i) {
    if (in_sizes[i] == B * T * N * C)      xp  = d_in[i];
    else if (in_sizes[i] == K * C)         cwp = d_in[i];
    else if (in_sizes[i] == 1)             cp  = d_in[i];
  }
  if (!xp)  xp  = d_in[0];
  if (!cwp) cwp = d_in[1];
  if (!cp)  cp  = d_in[n_in - 1];

  float* out0 = (float*)d_out;                 // [B,N,K]
  float* out1 = out0 + (size_t)B * N * K;      // [B,T,N,K]

  hipLaunchKernelGGL(hcd_kernel, dim3(B * NPAIRS), dim3(640), 0, stream,
                     (const float*)xp, (const float*)cwp, (const float*)cp,
                     out0, out1);
}

// Round 10
// 17.688 us; speedup vs baseline: 1.2637x; 1.2637x over previous
//
#include <hip/hip_runtime.h>

namespace {
constexpr int B = 8, T = 12, N = 325, C = 32, K = 100;
constexpr int NPB = 5;                 // nodes (waves) per block; 325 = 5*65
constexpr int NPAIRS = N / NPB;        // 65
constexpr int KT = 7;                  // 7 k-tiles of 16 -> 112 (pad 100->112)
constexpr int KP = KT * 16;
constexpr float EPSF = 1e-5f;
constexpr float MIN_NORM = 1e-15f;
}

typedef __attribute__((ext_vector_type(8))) short bf16x8;
typedef __attribute__((ext_vector_type(4))) float f32x4;

__device__ __forceinline__ unsigned short bf16_rne(float x) {
  unsigned int u = __float_as_uint(x);
  unsigned int r = u + 0x7FFFu + ((u >> 16) & 1u);
  return (unsigned short)(r >> 16);
}
__device__ __forceinline__ float bf16_f(unsigned short h) {
  return __uint_as_float(((unsigned int)h) << 16);
}

__global__ __launch_bounds__(320) void hcd_kernel(
    const float* __restrict__ x_g,       // [B,T,N,C]
    const float* __restrict__ cw,        // [K,C]
    const float* __restrict__ cptr,      // [1]
    float* __restrict__ out0,            // [B,N,K]
    float* __restrict__ out1)            // [B,T,N,K]
{
  __shared__ unsigned short yh[KP][C];   // bf16 hi of expmap0(cw)
  __shared__ unsigned short ylo[KP][C];  // bf16 residual
  __shared__ float y2l[KP];
  __shared__ float x2l[NPB][T];

  const int tid = threadIdx.x;
  const int b  = blockIdx.x / NPAIRS;
  const int np = blockIdx.x % NPAIRS;
  const int n0 = np * NPB;
  const float c  = cptr[0];
  const float sc = sqrtf(c);
  const float inv_c4 = 4.f / c;                 // (2/sqrt(c))^2
  const float HLN2 = 0.34657359028f;            // ln2/2
  const float TLOG2E = 2.88539008178f;          // 2*log2(e)

  // ---- threads 0..111: expmap0(centroids) -> bf16 hi/lo LDS ----
  if (tid < KP) {
    float y[C];
    float y2 = 0.f;
    if (tid < K) {
      float u2 = 0.f;
      #pragma unroll
      for (int q = 0; q < C / 4; ++q) {
        float4 v = *(const float4*)(cw + tid * C + 4 * q);
        y[4*q+0] = v.x; y[4*q+1] = v.y; y[4*q+2] = v.z; y[4*q+3] = v.w;
      }
      #pragma unroll
      for (int i = 0; i < C; ++i) u2 = fmaf(y[i], y[i], u2);
      float z = sc * fmaxf(sqrtf(u2), MIN_NORM);
      float E  = exp2f(z * TLOG2E);                       // e^(2z)
      float th = (E - 1.f) * __builtin_amdgcn_rcpf(E + 1.f);
      float f  = th * __builtin_amdgcn_rcpf(z);
      #pragma unroll
      for (int i = 0; i < C; ++i) y[i] *= f;
      y2 = f * f * u2;
    } else {
      #pragma unroll
      for (int i = 0; i < C; ++i) y[i] = 0.f;
    }
    #pragma unroll
    for (int i = 0; i < C; ++i) {
      unsigned short h = bf16_rne(y[i]);
      yh[tid][i]  = h;
      ylo[tid][i] = bf16_rne(y[i] - bf16_f(h));
    }
    y2l[tid] = y2;
  }

  // ---- threads 128..187: x squared norms (fp32, exact path) ----
  if (tid >= 128 && tid < 128 + NPB * T) {
    int i  = tid - 128;
    int nl = i / T, t = i - nl * T;
    const float* xr = x_g + ((size_t)(b * T + t) * N + (n0 + nl)) * C;
    float s = 0.f;
    #pragma unroll
    for (int q = 0; q < C / 4; ++q) {
      float4 v = *(const float4*)(xr + 4 * q);
      s = fmaf(v.x, v.x, s); s = fmaf(v.y, v.y, s);
      s = fmaf(v.z, v.z, s); s = fmaf(v.w, v.w, s);
    }
    x2l[nl][t] = s;
  }

  // ---- A-fragment: wave's node, 16 t-rows (12 real + 4 zero) ----
  const int wave = tid >> 6;            // 0..4 -> node
  const int lane = tid & 63;
  const int l16  = lane & 15;           // A row (t) / B col (k) / D col (k)
  const int g    = lane >> 4;           // k-chunk: elems 8g..8g+7
  const int n    = n0 + wave;

  const int trow = (l16 < T) ? l16 : 0;
  const float* xrow = x_g + (((size_t)(b * T + trow) * N + n) * C) + 8 * g;
  float4 v0 = *(const float4*)(xrow);
  float4 v1 = *(const float4*)(xrow + 4);
  if (l16 >= T) { v0 = make_float4(0,0,0,0); v1 = make_float4(0,0,0,0); }
  float xe[8] = {v0.x, v0.y, v0.z, v0.w, v1.x, v1.y, v1.z, v1.w};
  bf16x8 ah, al;
  #pragma unroll
  for (int i = 0; i < 8; ++i) {
    unsigned short h = bf16_rne(xe[i]);
    ah[i] = (short)h;
    al[i] = (short)bf16_rne(xe[i] - bf16_f(h));
  }
  __syncthreads();

  // ---- B-fragments from LDS (7 k-tiles, hi+lo) ----
  bf16x8 bh[KT], bl[KT];
  #pragma unroll
  for (int kt = 0; kt < KT; ++kt) {
    bh[kt] = *(const bf16x8*)&yh [16 * kt + l16][8 * g];
    bl[kt] = *(const bf16x8*)&ylo[16 * kt + l16][8 * g];
  }

  // ---- MFMA: dot = xh*yh + xh*yl + xl*yh ----
  f32x4 acc[KT];
  #pragma unroll
  for (int kt = 0; kt < KT; ++kt) {
    f32x4 a = {0.f, 0.f, 0.f, 0.f};
    a = __builtin_amdgcn_mfma_f32_16x16x32_bf16(al, bh[kt], a, 0, 0, 0);
    a = __builtin_amdgcn_mfma_f32_16x16x32_bf16(ah, bl[kt], a, 0, 0, 0);
    a = __builtin_amdgcn_mfma_f32_16x16x32_bf16(ah, bh[kt], a, 0, 0, 0);
    acc[kt] = a;
  }

  // ---- epilogue: D[row=4g+reg -> t][col=l16 -> k within tile] ----
  const float c2 = c * c;
  const float tc = 2.f * c;
  float x2r[4];
  #pragma unroll
  for (int reg = 0; reg < 4; ++reg) {
    int t = 4 * g + reg;
    x2r[reg] = x2l[wave][(t < T) ? t : 0];
  }

  #pragma unroll
  for (int kt = 0; kt < KT; ++kt) {
    const int k = 16 * kt + l16;
    const bool kv = (k < K);
    const float y2 = y2l[16 * kt + l16];
    float ps = 0.f;
    #pragma unroll
    for (int reg = 0; reg < 4; ++reg) {
      const int t = 4 * g + reg;
      const bool tv = (t < T);
      const float dot = acc[kt][reg];
      const float x2 = x2r[reg];
      const float xy = -dot;                             // dot(-x, y)
      const float A  = fmaf(tc, xy, 1.f) + c * y2;       // 1 + 2c*xy + c*y2
      const float Bc = 1.f - c * x2;                     // 1 - c*x2
      float num2 = A * A * x2 + Bc * Bc * y2 + 2.f * A * Bc * xy;
      num2 = fmaxf(num2, 0.f);
      float den = fmaf(c2 * x2, y2, fmaf(tc, xy, 1.f));
      den = fmaxf(den, MIN_NORM);
      float s_ = sc * __builtin_amdgcn_sqrtf(num2);
      s_ = fminf(s_, (1.f - EPSF) * den);                // z <= 1-eps
      float r  = (den + s_) * __builtin_amdgcn_rcpf(den - s_);
      float at = HLN2 * __builtin_amdgcn_logf(r);        // atanh(z)
      float d2 = inv_c4 * at * at;
      if (tv & kv)
        out1[(((size_t)(b * T + t)) * N + n) * K + k] = d2;
      ps += tv ? d2 : 0.f;
    }
    // reduce over the 4 row-groups (lanes l, l^16, l^32, l^48)
    ps += __shfl_xor(ps, 16);
    ps += __shfl_xor(ps, 32);
    if (g == 0 && kv)
      out0[((size_t)b * N + n) * K + k] = ps * (1.f / (float)N);
  }
}

extern "C" void kernel_launch(void* const* d_in, const int* in_sizes, int n_in,
                              void* d_out, int out_size, void* d_ws, size_t ws_size,
                              hipStream_t stream) {
  // identify inputs by size (order-proof): node 998400, centroids 3200, c 1
  const void* xp = nullptr; const void* cwp = nullptr; const void* cp = nullptr;
  for (int i = 0; i < n_in; ++i) {
    if (in_sizes[i] == B * T * N * C)      xp  = d_in[i];
    else if (in_sizes[i] == K * C)         cwp = d_in[i];
    else if (in_sizes[i] == 1)             cp  = d_in[i];
  }
  if (!xp)  xp  = d_in[0];
  if (!cwp) cwp = d_in[1];
  if (!cp)  cp  = d_in[n_in - 1];

  float* out0 = (float*)d_out;                 // [B,N,K]
  float* out1 = out0 + (size_t)B * N * K;      // [B,T,N,K]

  hipLaunchKernelGGL(hcd_kernel, dim3(B * NPAIRS), dim3(320), 0, stream,
                     (const float*)xp, (const float*)cwp, (const float*)cp,
                     out0, out1);
}